// Round 8
// baseline (207.767 us; speedup 1.0000x reference)
//
#include <hip/hip_runtime.h>
#include <math.h>

// SelfNorm split into two pure streaming passes:
//   K1 (stats): per-plane mean/std + both MLPs -> coeff[plane] = {a, bb}
//               where out = x*a + bb, a = std_w, bb = mean*(mean_w - std_w).
//               Read-only stream of x (102.8 MB), writes 64 KB of coeffs.
//   K2 (apply): out[i] = x[i]*a[p] + bb[p] — copy-shaped; x is L3-resident
//               after K1, so this is ~pure write stream.
// Rationale: fused variants phase-lock the whole GPU (read-burst / silent
// compute / write-burst), pinning DRAM duty cycle at ~50%. Split passes are
// each the access pattern measured at 5-6.7 TB/s on this chip.

typedef float f32x4 __attribute__((ext_vector_type(4)));
typedef float f32x2 __attribute__((ext_vector_type(2)));

constexpr int N_HW  = 56 * 56;   // 3136 floats per plane = 784 vec4
constexpr int BLOCK = 256;
constexpr int PLANES = 32 * 256; // 8192
constexpr float EPS = 1e-5f;

// ---------------- K1: stats + MLP -> coeff ----------------
__global__ __launch_bounds__(BLOCK) void stats_kernel(
    const float* __restrict__ x,
    const float* __restrict__ W1m, const float* __restrict__ b1m,
    const float* __restrict__ W2m, const float* __restrict__ b2m,
    const float* __restrict__ W1s, const float* __restrict__ b1s,
    const float* __restrict__ W2s, const float* __restrict__ b2s,
    f32x2* __restrict__ coeff)
{
    const int tid  = threadIdx.x;
    const int wave = tid >> 6;
    const int lane = tid & 63;
    const int plane = blockIdx.x * 4 + wave;          // 2048 blocks x 4 waves
    const long long base = (long long)plane * N_HW;
    const f32x4* __restrict__ src = (const f32x4*)(x + base);

    // 12 vec4 + 1 scalar tail per lane, all independent loads
    f32x4 r[12];
    #pragma unroll
    for (int k = 0; k < 12; ++k) r[k] = src[k * 64 + lane];
    float rt = x[base + 3072 + lane];

    float sum   = rt;
    float sumsq = rt * rt;
    #pragma unroll
    for (int k = 0; k < 12; ++k) {
        sum   += (r[k].x + r[k].y) + (r[k].z + r[k].w);
        sumsq += (r[k].x * r[k].x + r[k].y * r[k].y)
               + (r[k].z * r[k].z + r[k].w * r[k].w);
    }

    #pragma unroll
    for (int off = 1; off < 64; off <<= 1) {
        sum   += __shfl_xor(sum, off, 64);
        sumsq += __shfl_xor(sumsq, off, 64);
    }

    const float mean = sum * (1.0f / (float)N_HW);
    const float var  = (sumsq - sum * mean) * (1.0f / (float)(N_HW - 1)); // ddof=1
    const float stdv = sqrtf(var + EPS);

    float accm = b2m[0];
    float accs = b2s[0];
    #pragma unroll
    for (int j = 0; j < 16; ++j) {
        float hm = fmaf(W1m[j * 2 + 1], stdv, fmaf(W1m[j * 2], mean, b1m[j]));
        accm = fmaf(W2m[j], fmaxf(hm, 0.f), accm);
        float hs = fmaf(W1s[j * 2 + 1], stdv, fmaf(W1s[j * 2], mean, b1s[j]));
        accs = fmaf(W2s[j], fmaxf(hs, 0.f), accs);
    }
    const float mean_w = 1.0f / (1.0f + expf(-accm));
    const float std_w  = 1.0f / (1.0f + expf(-accs));

    if (lane == 0) {
        f32x2 c;
        c.x = std_w;                       // a
        c.y = mean * (mean_w - std_w);     // bb
        coeff[plane] = c;
    }
}

// ---------------- K2: out = x*a + bb (copy-shaped) ----------------
// Two planes per block: waves 0-1 -> plane0, waves 2-3 -> plane1.
// Each wave-pair (128 thr) covers 784 vec4 = 128*6 + 16.
__global__ __launch_bounds__(BLOCK) void apply_kernel(
    const float* __restrict__ x,
    const f32x2* __restrict__ coeff,
    float* __restrict__ out)
{
    const int tid  = threadIdx.x;
    const int half = tid >> 7;            // 0 or 1
    const int t    = tid & 127;           // index within the half-block
    const int plane = blockIdx.x * 2 + half;   // 4096 blocks x 2 planes
    const f32x2 c = coeff[plane];              // uniform per half -> scalar load
    const float a = c.x, bb = c.y;

    const long long base = (long long)plane * N_HW;
    const f32x4* __restrict__ src = (const f32x4*)(x + base);
    f32x4* __restrict__ dst       = (f32x4*)(out + base);

    f32x4 v[6];
    #pragma unroll
    for (int k = 0; k < 6; ++k) v[k] = src[t + 128 * k];
    f32x4 vt;
    if (t < 16) vt = src[768 + t];

    #pragma unroll
    for (int k = 0; k < 6; ++k) {
        f32x4 o;
        o.x = fmaf(v[k].x, a, bb);
        o.y = fmaf(v[k].y, a, bb);
        o.z = fmaf(v[k].z, a, bb);
        o.w = fmaf(v[k].w, a, bb);
        dst[t + 128 * k] = o;
    }
    if (t < 16) {
        f32x4 o;
        o.x = fmaf(vt.x, a, bb);
        o.y = fmaf(vt.y, a, bb);
        o.z = fmaf(vt.z, a, bb);
        o.w = fmaf(vt.w, a, bb);
        dst[768 + t] = o;
    }
}

extern "C" void kernel_launch(void* const* d_in, const int* in_sizes, int n_in,
                              void* d_out, int out_size, void* d_ws, size_t ws_size,
                              hipStream_t stream) {
    const float* x   = (const float*)d_in[0];
    const float* W1m = (const float*)d_in[1];
    const float* b1m = (const float*)d_in[2];
    const float* W2m = (const float*)d_in[3];
    const float* b2m = (const float*)d_in[4];
    const float* W1s = (const float*)d_in[5];
    const float* b1s = (const float*)d_in[6];
    const float* W2s = (const float*)d_in[7];
    const float* b2s = (const float*)d_in[8];
    float* out = (float*)d_out;
    f32x2* coeff = (f32x2*)d_ws;   // 8192 * 8 B = 64 KB scratch

    stats_kernel<<<PLANES / 4, BLOCK, 0, stream>>>(
        x, W1m, b1m, W2m, b2m, W1s, b1s, W2s, b2s, coeff);
    apply_kernel<<<PLANES / 2, BLOCK, 0, stream>>>(x, coeff, out);
}

// Round 10
// 198.956 us; speedup vs baseline: 1.0443x; 1.0443x over previous
//
#include <hip/hip_runtime.h>
#include <math.h>

// SelfNorm fused, LONG-LIVED WAVES + register double-buffer pipeline.
// out = x*a + bb with a = std_w, bb = mean*(mean_w - std_w)  (std cancels).
// Each wave owns 4 planes; while plane k is reduced/applied/stored, plane
// k+1's 13 loads are already in flight (ping-pong A/B reg buffers, fully
// unrolled -> static indexing, no scratch). 2048 waves of 64 lanes;
// plane = 3136 floats = 64 lanes x (12 vec4 + 1 tail float).

typedef float f32x4 __attribute__((ext_vector_type(4)));

constexpr int N_HW   = 56 * 56;    // 3136
constexpr int BLOCK  = 256;        // 4 waves/block
constexpr int NWAVES = 2048;       // total waves; 4 planes each = 8192 planes
constexpr float EPS  = 1e-5f;

__global__ __launch_bounds__(BLOCK, 2) void selfnorm_kernel(
    const float* __restrict__ x,
    const float* __restrict__ W1m, const float* __restrict__ b1m,
    const float* __restrict__ W2m, const float* __restrict__ b2m,
    const float* __restrict__ W1s, const float* __restrict__ b1s,
    const float* __restrict__ W2s, const float* __restrict__ b2s,
    float* __restrict__ out)
{
    const int tid  = threadIdx.x;
    const int lane = tid & 63;
    const int wid  = blockIdx.x * 4 + (tid >> 6);   // 0..2047

    // ---- load a full plane into 12 vec4 regs + 1 tail float ----
    auto LOAD = [&](f32x4* r, float& rt, int plane) {
        const float* src = x + (long long)plane * N_HW;
        const f32x4* sv = (const f32x4*)src;
        #pragma unroll
        for (int k = 0; k < 12; ++k) r[k] = sv[k * 64 + lane];
        rt = src[3072 + lane];
    };

    // ---- reduce + MLPs + apply + store one plane ----
    auto PROCESS = [&](const f32x4* r, float rt, int plane) {
        float sum   = rt;
        float sumsq = rt * rt;
        #pragma unroll
        for (int k = 0; k < 12; ++k) {
            sum   += (r[k].x + r[k].y) + (r[k].z + r[k].w);
            sumsq += (r[k].x * r[k].x + r[k].y * r[k].y)
                   + (r[k].z * r[k].z + r[k].w * r[k].w);
        }
        #pragma unroll
        for (int off = 1; off < 64; off <<= 1) {
            sum   += __shfl_xor(sum, off, 64);
            sumsq += __shfl_xor(sumsq, off, 64);
        }
        const float mean = sum * (1.0f / (float)N_HW);
        const float var  = (sumsq - sum * mean) * (1.0f / (float)(N_HW - 1));
        const float stdv = sqrtf(var + EPS);

        float accm = b2m[0];
        float accs = b2s[0];
        #pragma unroll
        for (int j = 0; j < 16; ++j) {
            float hm = fmaf(W1m[j*2+1], stdv, fmaf(W1m[j*2], mean, b1m[j]));
            accm = fmaf(W2m[j], fmaxf(hm, 0.f), accm);
            float hs = fmaf(W1s[j*2+1], stdv, fmaf(W1s[j*2], mean, b1s[j]));
            accs = fmaf(W2s[j], fmaxf(hs, 0.f), accs);
        }
        const float mean_w = 1.0f / (1.0f + expf(-accm));
        const float std_w  = 1.0f / (1.0f + expf(-accs));
        const float a  = std_w;
        const float bb = mean * (mean_w - std_w);

        float* dstp = out + (long long)plane * N_HW;
        f32x4* dv = (f32x4*)dstp;
        #pragma unroll
        for (int k = 0; k < 12; ++k) {
            f32x4 o;
            o.x = fmaf(r[k].x, a, bb);
            o.y = fmaf(r[k].y, a, bb);
            o.z = fmaf(r[k].z, a, bb);
            o.w = fmaf(r[k].w, a, bb);
            dv[k * 64 + lane] = o;
        }
        dstp[3072 + lane] = fmaf(rt, a, bb);
    };

    // ---- 4-plane pipeline, explicit ping-pong (all indices static) ----
    f32x4 A[12], B[12];
    float At, Bt;

    const int p0 = wid;
    const int p1 = wid + NWAVES;
    const int p2 = wid + 2 * NWAVES;
    const int p3 = wid + 3 * NWAVES;

    LOAD(A, At, p0);          // plane 0 in flight
    LOAD(B, Bt, p1);          // plane 1 in flight behind it
    PROCESS(A, At, p0);       // waits only on A's 13 loads; B stays in flight
    LOAD(A, At, p2);          // refill A while B is processed
    PROCESS(B, Bt, p1);
    LOAD(B, Bt, p3);
    PROCESS(A, At, p2);
    PROCESS(B, Bt, p3);       // tail: nothing left to prefetch
}

extern "C" void kernel_launch(void* const* d_in, const int* in_sizes, int n_in,
                              void* d_out, int out_size, void* d_ws, size_t ws_size,
                              hipStream_t stream) {
    const float* x   = (const float*)d_in[0];
    const float* W1m = (const float*)d_in[1];
    const float* b1m = (const float*)d_in[2];
    const float* W2m = (const float*)d_in[3];
    const float* b2m = (const float*)d_in[4];
    const float* W1s = (const float*)d_in[5];
    const float* b1s = (const float*)d_in[6];
    const float* W2s = (const float*)d_in[7];
    const float* b2s = (const float*)d_in[8];
    float* out = (float*)d_out;

    selfnorm_kernel<<<NWAVES / 4, BLOCK, 0, stream>>>(
        x, W1m, b1m, W2m, b2m, W1s, b1s, W2s, b2s, out);
}